// Round 2
// baseline (393.411 us; speedup 1.0000x reference)
//
#include <hip/hip_runtime.h>
#include <stdint.h>

// LIF bitshift-decay scan: B=32, T=1024, N=1024, n_syn=2. fp32, bit-exact.
//
// R1 @392us showed the register-prefetch version serialized its loads
// (64 chunks x 32 loads x ~450cyc == 922k cyc == measured). This version
// forces batched memory-level parallelism with global_load_lds DMA:
//   - 1 wave per block, 64 consecutive neurons, 512 blocks (2 waves/CU).
//   - 16-step chunks, LDS double buffer (2 x 8 KB).
//   - per chunk: issue 32 wave-wide 256B DMA loads for chunk k+1,
//     compute chunk k from LDS, ONE s_waitcnt vmcnt(0), then store spikes.
//   - 32 loads + <=16 stores = 48 outstanding <= vmcnt queue depth 63.
//
// Numerics: identical expression order to the verified-bit-exact R1 kernel:
//   i = (i - i*sd) + x;  v = (v - v*md) + (i0 + i1);  spike-subtract 1.0.

#define TT 1024
#define NN 1024
#define BB 32
#define UU 16   // time-steps per chunk

__global__ __launch_bounds__(64, 1)
void lif_scan_kernel(const float* __restrict__ in, float* __restrict__ out) {
    __shared__ float sbuf[2][UU][2][64];   // [buf][t][syn][lane] = 16 KB

    const int lane = threadIdx.x;
    const int b  = blockIdx.x >> 4;        // 32 batches
    const int n0 = (blockIdx.x & 15) << 6; // 16 groups of 64 neurons

    // input:  ((b*T + t)*2 + s)*N + n  ->  gin + t*2048 + s*1024
    const float* gin  = in  + (size_t)b * TT * 2 * NN + n0 + lane;
    // output: (b*T + t)*N + n          ->  gout + t*1024
    float*       gout = out + (size_t)b * TT * NN     + n0 + lane;

    const float SD0 = 0.25f;   // 2^-2 (tau_syn=5)
    const float SD1 = 0.5f;    // 2^-1 (tau_syn=2)
    const float MD  = 0.125f;  // 2^-3 (tau_mem=10)

    float i0 = 0.0f, i1 = 0.0f, v = 0.0f;

    // ---- prologue: DMA-stage chunk 0 into buffer 0 ----
#pragma unroll
    for (int j = 0; j < UU; ++j) {
#pragma unroll
        for (int s = 0; s < 2; ++s) {
            __builtin_amdgcn_global_load_lds(
                (const float __attribute__((address_space(1)))*)(gin + j * 2048 + s * 1024),
                (float __attribute__((address_space(3)))*)(&sbuf[0][j][s][0]),
                4, 0, 0);
        }
    }
    __builtin_amdgcn_s_waitcnt(0x0F70);   // vmcnt(0) only
    asm volatile("" ::: "memory");

    int p = 0;
    for (int tc = 0; tc < TT; tc += UU, p ^= 1) {
        // ---- issue DMA for chunk k+1 into the other buffer ----
        if (tc + UU < TT) {
            const float* gnext = gin + (size_t)(tc + UU) * 2048;
#pragma unroll
            for (int j = 0; j < UU; ++j) {
#pragma unroll
                for (int s = 0; s < 2; ++s) {
                    __builtin_amdgcn_global_load_lds(
                        (const float __attribute__((address_space(1)))*)(gnext + j * 2048 + s * 1024),
                        (float __attribute__((address_space(3)))*)(&sbuf[p ^ 1][j][s][0]),
                        4, 0, 0);
                }
            }
        }

        // ---- compute chunk k from LDS; buffer spikes in registers ----
        float spk[UU];
#pragma unroll
        for (int j = 0; j < UU; ++j) {
            float x0 = sbuf[p][j][0][lane];
            float x1 = sbuf[p][j][1][lane];
            i0 = (i0 - i0 * SD0) + x0;
            i1 = (i1 - i1 * SD1) + x1;
            float vd = v - v * MD;
            v = vd + (i0 + i1);
            float s_ = (v >= 1.0f) ? 1.0f : 0.0f;
            v -= s_;                       // membrane-subtract reset (thr=1.0)
            spk[j] = s_;
        }

        // ---- one wait per chunk: next chunk staged (+ old stores drained) ----
        __builtin_amdgcn_s_waitcnt(0x0F70);   // vmcnt(0) only
        asm volatile("" ::: "memory");

        // ---- store this chunk's spikes (overlap with next chunk) ----
        float* go = gout + (size_t)tc * NN;
#pragma unroll
        for (int j = 0; j < UU; ++j) go[j * NN] = spk[j];
    }
}

extern "C" void kernel_launch(void* const* d_in, const int* in_sizes, int n_in,
                              void* d_out, int out_size, void* d_ws, size_t ws_size,
                              hipStream_t stream) {
    const float* in = (const float*)d_in[0];
    float* out = (float*)d_out;
    dim3 grid(BB * NN / 64);   // 512 one-wave blocks -> 2 waves/CU
    dim3 block(64);
    hipLaunchKernelGGL(lif_scan_kernel, grid, block, 0, stream, in, out);
}